// Round 6
// baseline (434.959 us; speedup 1.0000x reference)
//
#include <hip/hip_runtime.h>

#define NG 20000
#define BOFF 12800000u   // flat-index offset of batch b+32: 32*K*N

// ---------- JAX threefry2x32, key = (0, 42) ----------
__device__ __forceinline__ void threefry2x32(unsigned x0, unsigned x1,
                                             unsigned& o0, unsigned& o1) {
  const unsigned ks0 = 0u;
  const unsigned ks1 = 42u;
  const unsigned ks2 = 0x1BD11BDAu ^ 0u ^ 42u;
  x0 += ks0; x1 += ks1;
#define TFR(r) { x0 += x1; x1 = (x1 << (r)) | (x1 >> (32 - (r))); x1 ^= x0; }
  TFR(13) TFR(15) TFR(26) TFR(6)
  x0 += ks1; x1 += ks2 + 1u;
  TFR(17) TFR(29) TFR(16) TFR(24)
  x0 += ks2; x1 += ks0 + 2u;
  TFR(13) TFR(15) TFR(26) TFR(6)
  x0 += ks0; x1 += ks1 + 3u;
  TFR(17) TFR(29) TFR(16) TFR(24)
  x0 += ks1; x1 += ks2 + 4u;
  TFR(13) TFR(15) TFR(26) TFR(6)
  x0 += ks2; x1 += ks0 + 5u;
#undef TFR
  o0 = x0; o1 = x1;
}

// JAX threefry_partitionable: bits(i) = o0 ^ o1 of threefry((0,42),(0,i))
__device__ __forceinline__ unsigned tfbits(unsigned ctr) {
  unsigned o0, o1;
  threefry2x32(0u, ctr, o0, o1);
  return o0 ^ o1;
}

// bits -> u in [tiny, 1): 23-bit dyadic rational (exact in fp32/fp64)
__device__ __forceinline__ float ufrombits(unsigned bits) {
  const float f = __uint_as_float((bits >> 9) | 0x3f800000u) - 1.0f;
  return fmaxf(f, 1.17549435e-38f);
}

// exact fp64 gumbel
__device__ __forceinline__ double gumbel64(unsigned bits) {
  const double u = (double)ufrombits(bits);
  return -log(-log(u));
}

// pack fp64 score (top 49 monotone bits) + 15-bit (32767-n): u64 max == (score, then smaller n)
__device__ __forceinline__ unsigned long long packcell(double v, int n) {
  unsigned long long u = (unsigned long long)__double_as_longlong(v);
  u = (u >> 63) ? ~u : (u | 0x8000000000000000ull);
  return (u & 0xFFFFFFFFFFFF8000ull) | (unsigned long long)(32767 - n);
}

// ---------- prep: Wf=Wk@W1k (fp64), Q, qbT; c12 table; zero cells ----------
__global__ __launch_bounds__(128) void kprep(
    const float* __restrict__ pe, const float* __restrict__ Wq,
    const float* __restrict__ bq, const float* __restrict__ Wk,
    const float* __restrict__ bk, const float* __restrict__ W1,
    const float* __restrict__ b1, const float* __restrict__ w2,
    double* __restrict__ Wfd, double* __restrict__ qbT,
    float* __restrict__ Qm, unsigned long long* __restrict__ cells,
    double2* __restrict__ c12) {
  __shared__ float L[512];
  __shared__ double Ld[128];
  const int t = threadIdx.x;
  const int bid = blockIdx.x;
  if (bid < 256) {
    L[t] = Wk[bid * 128 + t];
    __syncthreads();
    double acc = 0.0;
    #pragma unroll 8
    for (int j = 0; j < 128; ++j)
      acc = fma((double)L[j], (double)W1[(128 + j) * 128 + t], acc);
    Wfd[bid * 128 + t] = acc;
  } else if (bid < 320) {
    const int b = bid - 256;
    #pragma unroll
    for (int i = 0; i < 4; ++i) L[t + 128 * i] = pe[b * 512 + t + 128 * i];
    __syncthreads();
    double q = (double)bq[t];
    #pragma unroll 4
    for (int f = 0; f < 512; ++f)
      q = fma((double)L[f], (double)Wq[f * 128 + t], q);
    Qm[b * 128 + t] = (float)q;   // epilogue path stays fp32
    Ld[t] = q;
    __syncthreads();
    // qb[b,d=t] = Q@W1[:128] + b1 + bk@W1[128:]; store transposed qbT[d][b]
    double acc = (double)b1[t];
    #pragma unroll 4
    for (int j = 0; j < 128; ++j) {
      acc = fma(Ld[j], (double)W1[j * 128 + t], acc);
      acc = fma((double)bk[j], (double)W1[(128 + j) * 128 + t], acc);
    }
    qbT[t * 64 + b] = acc;
  } else {
    for (int i = t; i < 1280; i += 128) cells[i] = 0ull;
    const double w2d = (double)w2[t];
    c12[t] = make_double2(0.55 * w2d, 0.45 * w2d);
  }
}

// ---------- kpT[d][n] = (ge @ Wf)^T : fp64, double-buffered, transposed store ----------
__global__ __launch_bounds__(128) void kgemm(
    const float* __restrict__ ge, const double* __restrict__ Wfd,
    double* __restrict__ kpT) {
  const int t = threadIdx.x;          // d = t
  const int g0 = blockIdx.x * 8;      // 2500 blocks * 8 genes
  const float* gb = ge + (size_t)g0 * 256;
  double acc[8];
  #pragma unroll
  for (int g = 0; g < 8; ++g) acc[g] = 0.0;

  float4 a_cur[8];
  double w_cur[4];
  #pragma unroll
  for (int g = 0; g < 8; ++g) a_cur[g] = *(const float4*)(gb + g * 256);
  #pragma unroll
  for (int j = 0; j < 4; ++j) w_cur[j] = Wfd[j * 128 + t];

  for (int f = 0; f < 256; f += 4) {
    const int fn = (f + 4) & 255;     // wrap: last prefetch re-reads f=0 (unused)
    float4 a_nxt[8];
    double w_nxt[4];
    #pragma unroll
    for (int g = 0; g < 8; ++g) a_nxt[g] = *(const float4*)(gb + g * 256 + fn);
    #pragma unroll
    for (int j = 0; j < 4; ++j) w_nxt[j] = Wfd[(fn + j) * 128 + t];
    #pragma unroll
    for (int g = 0; g < 8; ++g) {
      acc[g] = fma((double)a_cur[g].x, w_cur[0], acc[g]);
      acc[g] = fma((double)a_cur[g].y, w_cur[1], acc[g]);
      acc[g] = fma((double)a_cur[g].z, w_cur[2], acc[g]);
      acc[g] = fma((double)a_cur[g].w, w_cur[3], acc[g]);
    }
    #pragma unroll
    for (int g = 0; g < 8; ++g) a_cur[g] = a_nxt[g];
    #pragma unroll
    for (int j = 0; j < 4; ++j) w_cur[j] = w_nxt[j];
  }
  double* row = kpT + (size_t)t * NG + g0;   // 64B contiguous per thread
  #pragma unroll
  for (int j = 0; j < 4; ++j)
    *(double2*)(row + 2 * j) = make_double2(acc[2 * j], acc[2 * j + 1]);
}

// ---------- sim[b][n] (fp64) + simE[b][n]=exp(2*sim) (fp32); coalesced kpT reads ----------
__global__ __launch_bounds__(64) void ksim(
    const double* __restrict__ kpT, const double* __restrict__ qbT,
    const double2* __restrict__ c12, double* __restrict__ simd,
    float* __restrict__ simE) {
  const int lane = threadIdx.x;
  const int n = blockIdx.x * 64 + lane;           // 313 x-blocks
  const int b0 = blockIdx.y * 8;                  // 8 y-blocks * 8 batches
  const int nc = min(n, NG - 1);
  double acc[8];
  #pragma unroll
  for (int j = 0; j < 8; ++j) acc[j] = 0.0;
  for (int d = 0; d < 128; ++d) {
    const double kv = kpT[(size_t)d * NG + nc];   // coalesced across lanes
    const double2 cc = c12[d];                    // uniform -> s_load
    const double* qr = qbT + d * 64 + b0;         // uniform -> s_load
    #pragma unroll
    for (int j = 0; j < 8; ++j) {
      const double tt = qr[j] + kv;
      acc[j] = fma(tt, cc.x, acc[j]);
      acc[j] = fma(fabs(tt), cc.y, acc[j]);
    }
  }
  if (n < NG) {
    #pragma unroll
    for (int j = 0; j < 8; ++j) {
      simd[(size_t)(b0 + j) * NG + n] = acc[j];
      simE[(size_t)(b0 + j) * NG + n] = __expf((float)(2.0 * acc[j]));
    }
  }
}

// ---------- selection: ratio-form fp32 screen (1 log/candidate), fp64 exact at end ----------
// score = 2*sim + g, g = -log(e), e = -log(u):  max score == max E/e with E=exp(2*sim).
// E1/e1 > En/en  <=>  E1*en > En*e1  (all positive).  wave owns pair p (batches p, p+32).
__global__ __launch_bounds__(256) void ksel2(
    const double* __restrict__ simd, const float* __restrict__ simE,
    unsigned long long* __restrict__ cells) {
  const int t = threadIdx.x;
  const int wv = t >> 6;
  const int lane = t & 63;
  const int p = (int)(blockIdx.x & 7) * 4 + wv;   // pair 0..31
  const int c = (int)(blockIdx.x >> 3);           // chunk 0..246
  const int n0 = c * 81;
  const int k = lane % 20;
  const int gi = lane / 20;                       // lanes 60..63: gi=3, masked off
  const float* seA = simE + (size_t)p * NG;
  const float* seB = simE + (size_t)(p + 32) * NG;
  const unsigned kbase = (unsigned)(p * 20 + k) * (unsigned)NG;

  float E1A = 0.f, e1A = 1.f, E2A = 0.f, e2A = 1.f;
  float E1B = 0.f, e1B = 1.f, E2B = 0.f, e2B = 1.f;
  int n1A = n0, n1B = n0;
  unsigned idx = kbase + (unsigned)(n0 + gi);

  for (int it = 0; it < 27; ++it) {
    const int n = n0 + it * 3 + gi;
    const bool v = (lane < 60) && (n < NG);
    const int nc = min(n, NG - 1);
    const unsigned bA = tfbits(idx);
    const unsigned bB = tfbits(idx + BOFF);
    idx += 3;
    const float eA = __log2f(ufrombits(bA)) * (-0.69314718056f);  // = -log(u) > 0
    const float eB = __log2f(ufrombits(bB)) * (-0.69314718056f);
    const float EnA = v ? seA[nc] : 0.f;
    const float EnB = v ? seB[nc] : 0.f;
    // batch A: update (E1,e1,n1) and value-only runner-up (E2,e2)
    {
      const bool g1 = EnA * e1A > E1A * eA;
      const bool g2 = EnA * e2A > E2A * eA;
      E2A = g1 ? E1A : (g2 ? EnA : E2A);
      e2A = g1 ? e1A : (g2 ? eA : e2A);
      E1A = g1 ? EnA : E1A;
      e1A = g1 ? eA : e1A;
      n1A = g1 ? n : n1A;
    }
    // batch B
    {
      const bool g1 = EnB * e1B > E1B * eB;
      const bool g2 = EnB * e2B > E2B * eB;
      E2B = g1 ? E1B : (g2 ? EnB : E2B);
      e2B = g1 ? e1B : (g2 ? eB : e2B);
      E1B = g1 ? EnB : E1B;
      e1B = g1 ? eB : e1B;
      n1B = g1 ? n : n1B;
    }
  }

  // exact fp64 eval of screen winners; rescan window iff top-2 ratio < 1+2e-3 (>> 5e-6 screen err)
  unsigned long long pbA = 0ull, pbB = 0ull;
  if (lane < 60) {
    pbA = packcell(2.0 * simd[(size_t)p * NG + n1A] + gumbel64(tfbits(kbase + (unsigned)n1A)), n1A);
    if (E1A * e2A < E2A * e1A * 1.002f) {
      unsigned ii = kbase + (unsigned)(n0 + gi);
      for (int it = 0; it < 27; ++it) {
        const int n = n0 + it * 3 + gi;
        if (n < NG) {
          const unsigned long long u = packcell(
              2.0 * simd[(size_t)p * NG + n] + gumbel64(tfbits(ii)), n);
          if (u > pbA) pbA = u;
        }
        ii += 3;
      }
    }
    pbB = packcell(2.0 * simd[(size_t)(p + 32) * NG + n1B] +
                   gumbel64(tfbits(kbase + (unsigned)n1B + BOFF)), n1B);
    if (E1B * e2B < E2B * e1B * 1.002f) {
      unsigned ii = kbase + (unsigned)(n0 + gi) + BOFF;
      for (int it = 0; it < 27; ++it) {
        const int n = n0 + it * 3 + gi;
        if (n < NG) {
          const unsigned long long u = packcell(
              2.0 * simd[(size_t)(p + 32) * NG + n] + gumbel64(tfbits(ii)), n);
          if (u > pbB) pbB = u;
        }
        ii += 3;
      }
    }
  }

  // fold gi slots (lanes +20, +40), then one atomic per (batch, k)
  #pragma unroll
  for (int sh = 20; sh <= 40; sh += 20) {
    const unsigned long long oA = __shfl(pbA, lane + sh, 64);
    const unsigned long long oB = __shfl(pbB, lane + sh, 64);
    if (lane < 20) {
      if (oA > pbA) pbA = oA;
      if (oB > pbB) pbB = oB;
    }
  }
  if (lane < 20 && pbA) atomicMax(&cells[p * 20 + lane], pbA);
  if (lane < 20 && pbB) atomicMax(&cells[(p + 32) * 20 + lane], pbB);
}

// ---------- epilogue (fp32): 5 interleaved V-GEMVs per wave, softmax over K, context ----------
__global__ __launch_bounds__(256) void kfinal(
    const float* __restrict__ ge, const float* __restrict__ Wv,
    const float* __restrict__ bv, const float* __restrict__ Qm,
    const unsigned long long* __restrict__ cells, float* __restrict__ out) {
  const int b = blockIdx.x;
  const int t = threadIdx.x;
  const int wv = t >> 6;
  const int lane = t & 63;
  __shared__ float sc[20];
  __shared__ float ctxp[4][128];
  const float2 qv = ((const float2*)(Qm + b * 128))[lane];
  const float2 bvv = ((const float2*)bv)[lane];
  const float* gr[5];
  float2 V[5];
  #pragma unroll
  for (int j = 0; j < 5; ++j) {
    const unsigned long long cell = cells[b * 20 + wv * 5 + j];
    const int n = 32767 - (int)(cell & 0x7FFFull);
    gr[j] = ge + (size_t)n * 256;
    V[j] = bvv;
  }
  for (int f = 0; f < 256; f += 4) {
    const float2 w0 = ((const float2*)(Wv + (size_t)(f + 0) * 128))[lane];
    const float2 w1 = ((const float2*)(Wv + (size_t)(f + 1) * 128))[lane];
    const float2 w2_ = ((const float2*)(Wv + (size_t)(f + 2) * 128))[lane];
    const float2 w3 = ((const float2*)(Wv + (size_t)(f + 3) * 128))[lane];
    #pragma unroll
    for (int j = 0; j < 5; ++j) {
      const float4 gv = *(const float4*)(gr[j] + f);   // uniform -> s_load
      V[j].x = fmaf(gv.x, w0.x, V[j].x); V[j].y = fmaf(gv.x, w0.y, V[j].y);
      V[j].x = fmaf(gv.y, w1.x, V[j].x); V[j].y = fmaf(gv.y, w1.y, V[j].y);
      V[j].x = fmaf(gv.z, w2_.x, V[j].x); V[j].y = fmaf(gv.z, w2_.y, V[j].y);
      V[j].x = fmaf(gv.w, w3.x, V[j].x); V[j].y = fmaf(gv.w, w3.y, V[j].y);
    }
  }
  #pragma unroll
  for (int j = 0; j < 5; ++j) {
    float pr = qv.x * V[j].x + qv.y * V[j].y;
    #pragma unroll
    for (int off = 32; off; off >>= 1) pr += __shfl_xor(pr, off, 64);
    if (lane == 0) sc[wv * 5 + j] = pr * 0.08838834764831845f;  // 1/sqrt(128)
  }
  __syncthreads();
  float m = -3.0e38f;
  #pragma unroll
  for (int i = 0; i < 20; ++i) m = fmaxf(m, sc[i]);
  float s = 0.f;
  #pragma unroll
  for (int i = 0; i < 20; ++i) s += expf(sc[i] - m);
  const float inv = 1.0f / s;
  float c0 = 0.f, c1 = 0.f;
  #pragma unroll
  for (int j = 0; j < 5; ++j) {
    const float wk = expf(sc[wv * 5 + j] - m) * inv;
    c0 = fmaf(wk, V[j].x, c0);
    c1 = fmaf(wk, V[j].y, c1);
  }
  ctxp[wv][2 * lane] = c0;
  ctxp[wv][2 * lane + 1] = c1;
  __syncthreads();
  if (t < 128)
    out[b * 128 + t] = (ctxp[0][t] + ctxp[1][t]) + (ctxp[2][t] + ctxp[3][t]);
}

extern "C" void kernel_launch(void* const* d_in, const int* in_sizes, int n_in,
                              void* d_out, int out_size, void* d_ws, size_t ws_size,
                              hipStream_t stream) {
  (void)in_sizes; (void)n_in; (void)out_size; (void)ws_size;
  const float* pe = (const float*)d_in[0];
  const float* ge = (const float*)d_in[1];
  const float* Wq = (const float*)d_in[2];
  const float* bq = (const float*)d_in[3];
  const float* Wk = (const float*)d_in[4];
  const float* bk = (const float*)d_in[5];
  const float* Wv = (const float*)d_in[6];
  const float* bvp = (const float*)d_in[7];
  const float* W1 = (const float*)d_in[8];
  const float* b1 = (const float*)d_in[9];
  const float* w2 = (const float*)d_in[10];
  // d_in[11] = b2: uniform over n -> cancels in argmax; absent from output path.

  char* w = (char*)d_ws;
  double* Wfd = (double*)w;                              // 262144 B
  double* qbT = (double*)(w + 262144);                   // 65536 B
  float* Qm = (float*)(w + 327680);                      // 32768 B
  unsigned long long* cells =
      (unsigned long long*)(w + 360448);                 // 10240 B
  double2* c12 = (double2*)(w + 370688);                 // 2048 B
  double* kpT = (double*)(w + 372736);                   // 20,480,000 B
  double* simd = (double*)(w + 20852736);                // 10,240,000 B
  float* simE = (float*)(w + 31092736);                  // 5,120,000 B (~36.2 MB total)
  float* out = (float*)d_out;

  kprep<<<dim3(321), dim3(128), 0, stream>>>(pe, Wq, bq, Wk, bk, W1, b1, w2,
                                             Wfd, qbT, Qm, cells, c12);
  kgemm<<<dim3(2500), dim3(128), 0, stream>>>(ge, Wfd, kpT);
  ksim<<<dim3(313, 8), dim3(64), 0, stream>>>(kpT, qbT, c12, simd, simE);
  ksel2<<<dim3(1976), dim3(256), 0, stream>>>(simd, simE, cells);
  kfinal<<<dim3(64), dim3(256), 0, stream>>>(ge, Wv, bvp, Qm, cells, out);
}

// Round 7
// 333.927 us; speedup vs baseline: 1.3026x; 1.3026x over previous
//
#include <hip/hip_runtime.h>

#define NG 20000
#define BOFF 12800000u   // flat-index offset of batch b+32: 32*K*N

// ---------- JAX threefry2x32, key = (0, 42) ----------
__device__ __forceinline__ void threefry2x32(unsigned x0, unsigned x1,
                                             unsigned& o0, unsigned& o1) {
  const unsigned ks0 = 0u;
  const unsigned ks1 = 42u;
  const unsigned ks2 = 0x1BD11BDAu ^ 0u ^ 42u;
  x0 += ks0; x1 += ks1;
#define TFR(r) { x0 += x1; x1 = (x1 << (r)) | (x1 >> (32 - (r))); x1 ^= x0; }
  TFR(13) TFR(15) TFR(26) TFR(6)
  x0 += ks1; x1 += ks2 + 1u;
  TFR(17) TFR(29) TFR(16) TFR(24)
  x0 += ks2; x1 += ks0 + 2u;
  TFR(13) TFR(15) TFR(26) TFR(6)
  x0 += ks0; x1 += ks1 + 3u;
  TFR(17) TFR(29) TFR(16) TFR(24)
  x0 += ks1; x1 += ks2 + 4u;
  TFR(13) TFR(15) TFR(26) TFR(6)
  x0 += ks2; x1 += ks0 + 5u;
#undef TFR
  o0 = x0; o1 = x1;
}

// JAX threefry_partitionable: bits(i) = o0 ^ o1 of threefry((0,42),(0,i))
__device__ __forceinline__ unsigned tfbits(unsigned ctr) {
  unsigned o0, o1;
  threefry2x32(0u, ctr, o0, o1);
  return o0 ^ o1;
}

// fp32 fast-screen gumbel (hw log path); abs err vs fp64 < ~1e-5
__device__ __forceinline__ float gumbel32(unsigned bits) {
  float f = __uint_as_float((bits >> 9) | 0x3f800000u) - 1.0f;
  float u = fmaxf(f, 1.17549435e-38f);
  return -__logf(-__logf(u));
}

// exact fp64 gumbel; u is a 23-bit dyadic rational, exact in double
__device__ __forceinline__ double gumbel64(unsigned bits) {
  float f = __uint_as_float((bits >> 9) | 0x3f800000u) - 1.0f;
  double u = (double)fmaxf(f, 1.17549435e-38f);
  return -log(-log(u));
}

// pack fp64 score (top 49 monotone bits) + 15-bit (32767-n): u64 max == (score, then smaller n)
__device__ __forceinline__ unsigned long long packcell(double v, int n) {
  unsigned long long u = (unsigned long long)__double_as_longlong(v);
  u = (u >> 63) ? ~u : (u | 0x8000000000000000ull);
  return (u & 0xFFFFFFFFFFFF8000ull) | (unsigned long long)(32767 - n);
}

// ---------- prep: Wf=Wk@W1k (fp64), Q, qbT; c12 table; zero cells ----------
__global__ __launch_bounds__(128) void kprep(
    const float* __restrict__ pe, const float* __restrict__ Wq,
    const float* __restrict__ bq, const float* __restrict__ Wk,
    const float* __restrict__ bk, const float* __restrict__ W1,
    const float* __restrict__ b1, const float* __restrict__ w2,
    double* __restrict__ Wfd, double* __restrict__ qbT,
    float* __restrict__ Qm, unsigned long long* __restrict__ cells,
    double2* __restrict__ c12) {
  __shared__ float L[512];
  __shared__ double Ld[128];
  const int t = threadIdx.x;
  const int bid = blockIdx.x;
  if (bid < 256) {
    L[t] = Wk[bid * 128 + t];
    __syncthreads();
    double acc = 0.0;
    #pragma unroll 8
    for (int j = 0; j < 128; ++j)
      acc = fma((double)L[j], (double)W1[(128 + j) * 128 + t], acc);
    Wfd[bid * 128 + t] = acc;
  } else if (bid < 320) {
    const int b = bid - 256;
    #pragma unroll
    for (int i = 0; i < 4; ++i) L[t + 128 * i] = pe[b * 512 + t + 128 * i];
    __syncthreads();
    double q = (double)bq[t];
    #pragma unroll 4
    for (int f = 0; f < 512; ++f)
      q = fma((double)L[f], (double)Wq[f * 128 + t], q);
    Qm[b * 128 + t] = (float)q;   // epilogue path stays fp32
    Ld[t] = q;
    __syncthreads();
    // qb[b,d=t] = Q@W1[:128] + b1 + bk@W1[128:]; store transposed qbT[d][b]
    double acc = (double)b1[t];
    #pragma unroll 4
    for (int j = 0; j < 128; ++j) {
      acc = fma(Ld[j], (double)W1[j * 128 + t], acc);
      acc = fma((double)bk[j], (double)W1[(128 + j) * 128 + t], acc);
    }
    qbT[t * 64 + b] = acc;
  } else {
    for (int i = t; i < 1280; i += 128) cells[i] = 0ull;
    const double w2d = (double)w2[t];
    c12[t] = make_double2(0.55 * w2d, 0.45 * w2d);
  }
}

// ---------- kpT[d][n] = (ge @ Wf)^T : fp64, double-buffered, transposed store ----------
__global__ __launch_bounds__(128) void kgemm(
    const float* __restrict__ ge, const double* __restrict__ Wfd,
    double* __restrict__ kpT) {
  const int t = threadIdx.x;          // d = t
  const int g0 = blockIdx.x * 8;      // 2500 blocks * 8 genes
  const float* gb = ge + (size_t)g0 * 256;
  double acc[8];
  #pragma unroll
  for (int g = 0; g < 8; ++g) acc[g] = 0.0;

  float4 a_cur[8];
  double w_cur[4];
  #pragma unroll
  for (int g = 0; g < 8; ++g) a_cur[g] = *(const float4*)(gb + g * 256);
  #pragma unroll
  for (int j = 0; j < 4; ++j) w_cur[j] = Wfd[j * 128 + t];

  for (int f = 0; f < 256; f += 4) {
    const int fn = (f + 4) & 255;     // wrap: last prefetch re-reads f=0 (unused)
    float4 a_nxt[8];
    double w_nxt[4];
    #pragma unroll
    for (int g = 0; g < 8; ++g) a_nxt[g] = *(const float4*)(gb + g * 256 + fn);
    #pragma unroll
    for (int j = 0; j < 4; ++j) w_nxt[j] = Wfd[(fn + j) * 128 + t];
    #pragma unroll
    for (int g = 0; g < 8; ++g) {
      acc[g] = fma((double)a_cur[g].x, w_cur[0], acc[g]);
      acc[g] = fma((double)a_cur[g].y, w_cur[1], acc[g]);
      acc[g] = fma((double)a_cur[g].z, w_cur[2], acc[g]);
      acc[g] = fma((double)a_cur[g].w, w_cur[3], acc[g]);
    }
    #pragma unroll
    for (int g = 0; g < 8; ++g) a_cur[g] = a_nxt[g];
    #pragma unroll
    for (int j = 0; j < 4; ++j) w_cur[j] = w_nxt[j];
  }
  double* row = kpT + (size_t)t * NG + g0;   // 64B contiguous per thread
  #pragma unroll
  for (int j = 0; j < 4; ++j)
    *(double2*)(row + 2 * j) = make_double2(acc[2 * j], acc[2 * j + 1]);
}

// ---------- sim[b][n] (fp64); coalesced kpT reads, 4 batches/thread, kv prefetch ----------
__global__ __launch_bounds__(64) void ksim(
    const double* __restrict__ kpT, const double* __restrict__ qbT,
    const double2* __restrict__ c12, double* __restrict__ simd) {
  const int lane = threadIdx.x;
  const int n = blockIdx.x * 64 + lane;           // 313 x-blocks
  const int b0 = blockIdx.y * 4;                  // 16 y-blocks * 4 batches
  const int nc = min(n, NG - 1);
  double acc[4];
  #pragma unroll
  for (int j = 0; j < 4; ++j) acc[j] = 0.0;
  double kv_nxt = kpT[nc];
  for (int d = 0; d < 128; ++d) {
    const double kv = kv_nxt;
    if (d < 127) kv_nxt = kpT[(size_t)(d + 1) * NG + nc];  // coalesced prefetch
    const double2 cc = c12[d];                    // uniform -> s_load
    const double* qr = qbT + d * 64 + b0;         // uniform -> s_load
    #pragma unroll
    for (int j = 0; j < 4; ++j) {
      const double tt = qr[j] + kv;
      acc[j] = fma(tt, cc.x, acc[j]);
      acc[j] = fma(fabs(tt), cc.y, acc[j]);
    }
  }
  if (n < NG) {
    #pragma unroll
    for (int j = 0; j < 4; ++j) simd[(size_t)(b0 + j) * NG + n] = acc[j];
  }
}

// ---------- selection (R5-proven): single-pass fp32 top-2 screen, fp64 exact at end ----------
// wave owns pair p (batches p, p+32); lane = (k = lane%20, gi = lane/20 < 3);
// 247 chunks * 81 genes; 1976 blocks -> ~7.7 waves/SIMD.
__global__ __launch_bounds__(256) void ksel2(
    const double* __restrict__ simd, unsigned long long* __restrict__ cells) {
  const int t = threadIdx.x;
  const int wv = t >> 6;
  const int lane = t & 63;
  const int p = (int)(blockIdx.x & 7) * 4 + wv;   // pair 0..31
  const int c = (int)(blockIdx.x >> 3);           // chunk 0..246
  const int n0 = c * 81;
  const int nEnd = min(n0 + 81, NG);
  const int k = lane % 20;
  const int gi = lane / 20;
  const bool active = lane < 60;
  const double* sdA = simd + (size_t)p * NG;
  const double* sdB = simd + (size_t)(p + 32) * NG;
  const unsigned kbase = (unsigned)(p * 20 + k) * (unsigned)NG;

  float m1A = -3e38f, m2A = -3e38f, m1B = -3e38f, m2B = -3e38f;
  int n1A = -1, n2A = -1, n1B = -1, n2B = -1;
  unsigned c1A = 0, c2A = 0, c1B = 0, c2B = 0;

  for (int it = 0; it < 27; ++it) {
    const int n = n0 + it * 3 + gi;
    const bool v = active && (n < nEnd);
    const int nc = v ? n : n0;
    const unsigned idxA = kbase + (unsigned)nc;
    const unsigned bA = tfbits(idxA);
    const unsigned bB = tfbits(idxA + BOFF);
    const float s2A = v ? (float)(2.0 * sdA[nc]) : -3e38f;
    const float s2B = v ? (float)(2.0 * sdB[nc]) : -3e38f;
    const float sA = s2A + gumbel32(bA);
    const float sB = s2B + gumbel32(bB);
    if (sA > m1A) { m2A = m1A; n2A = n1A; c2A = c1A; m1A = sA; n1A = n; c1A = bA; }
    else if (sA > m2A) { m2A = sA; n2A = n; c2A = bA; }
    if (sB > m1B) { m2B = m1B; n2B = n1B; c2B = c1B; m1B = sB; n1B = n; c1B = bB; }
    else if (sB > m2B) { m2B = sB; n2B = n; c2B = bB; }
  }

  // exact fp64 for the fp32 winner (+ runner-up iff ambiguous: gap < 1e-4 >> 1e-5 screen err)
  unsigned long long pbA = 0ull, pbB = 0ull;
  if (n1A >= 0) {
    pbA = packcell(2.0 * sdA[n1A] + gumbel64(c1A), n1A);
    if (n2A >= 0 && (m1A - m2A) < 1e-4f) {
      const unsigned long long u2 = packcell(2.0 * sdA[n2A] + gumbel64(c2A), n2A);
      if (u2 > pbA) pbA = u2;
    }
  }
  if (n1B >= 0) {
    pbB = packcell(2.0 * sdB[n1B] + gumbel64(c1B), n1B);
    if (n2B >= 0 && (m1B - m2B) < 1e-4f) {
      const unsigned long long u2 = packcell(2.0 * sdB[n2B] + gumbel64(c2B), n2B);
      if (u2 > pbB) pbB = u2;
    }
  }

  // fold gi slots (lanes +20, +40), then one atomic per (batch, k)
  #pragma unroll
  for (int sh = 20; sh <= 40; sh += 20) {
    const unsigned long long oA = __shfl(pbA, lane + sh, 64);
    const unsigned long long oB = __shfl(pbB, lane + sh, 64);
    if (lane < 20) {
      if (oA > pbA) pbA = oA;
      if (oB > pbB) pbB = oB;
    }
  }
  if (lane < 20 && pbA) atomicMax(&cells[p * 20 + lane], pbA);
  if (lane < 20 && pbB) atomicMax(&cells[(p + 32) * 20 + lane], pbB);
}

// ---------- epilogue V: one wave per (b,k) GEMV; Vk + score to ws ----------
__global__ __launch_bounds__(256) void kfinalV(
    const float* __restrict__ ge, const float* __restrict__ Wv,
    const float* __restrict__ bv, const float* __restrict__ Qm,
    const unsigned long long* __restrict__ cells,
    float* __restrict__ Vws, float* __restrict__ scws) {
  const int t = threadIdx.x;
  const int wv = t >> 6;
  const int lane = t & 63;
  const int task = blockIdx.x * 4 + wv;   // 320 blocks -> 1280 tasks = (b,k)
  const int b = task / 20;
  const unsigned long long cell = cells[task];
  const int n = 32767 - (int)(cell & 0x7FFFull);
  const float* gr = ge + (size_t)n * 256;
  const float2 qv = ((const float2*)(Qm + b * 128))[lane];
  float2 V = ((const float2*)bv)[lane];
  for (int f = 0; f < 256; f += 4) {
    const float4 gv = *(const float4*)(gr + f);   // wave-uniform -> s_load
    const float2 w0 = ((const float2*)(Wv + (size_t)(f + 0) * 128))[lane];
    const float2 w1 = ((const float2*)(Wv + (size_t)(f + 1) * 128))[lane];
    const float2 w2_ = ((const float2*)(Wv + (size_t)(f + 2) * 128))[lane];
    const float2 w3 = ((const float2*)(Wv + (size_t)(f + 3) * 128))[lane];
    V.x = fmaf(gv.x, w0.x, V.x); V.y = fmaf(gv.x, w0.y, V.y);
    V.x = fmaf(gv.y, w1.x, V.x); V.y = fmaf(gv.y, w1.y, V.y);
    V.x = fmaf(gv.z, w2_.x, V.x); V.y = fmaf(gv.z, w2_.y, V.y);
    V.x = fmaf(gv.w, w3.x, V.x); V.y = fmaf(gv.w, w3.y, V.y);
  }
  ((float2*)(Vws + (size_t)task * 128))[lane] = V;
  float pr = qv.x * V.x + qv.y * V.y;
  #pragma unroll
  for (int off = 32; off; off >>= 1) pr += __shfl_xor(pr, off, 64);
  if (lane == 0) scws[task] = pr * 0.08838834764831845f;  // 1/sqrt(128)
}

// ---------- epilogue C: softmax over K=20, weighted context sum ----------
__global__ __launch_bounds__(128) void kfinalC(
    const float* __restrict__ Vws, const float* __restrict__ scws,
    float* __restrict__ out) {
  const int b = blockIdx.x;
  const int t = threadIdx.x;   // t = d
  float sc[20];
  float m = -3.0e38f;
  #pragma unroll
  for (int i = 0; i < 20; ++i) { sc[i] = scws[b * 20 + i]; m = fmaxf(m, sc[i]); }
  float s = 0.f;
  #pragma unroll
  for (int i = 0; i < 20; ++i) { sc[i] = expf(sc[i] - m); s += sc[i]; }
  const float inv = 1.0f / s;
  float acc = 0.f;
  #pragma unroll 4
  for (int i = 0; i < 20; ++i)
    acc = fmaf(sc[i] * inv, Vws[(size_t)(b * 20 + i) * 128 + t], acc);
  out[b * 128 + t] = acc;
}

extern "C" void kernel_launch(void* const* d_in, const int* in_sizes, int n_in,
                              void* d_out, int out_size, void* d_ws, size_t ws_size,
                              hipStream_t stream) {
  (void)in_sizes; (void)n_in; (void)out_size; (void)ws_size;
  const float* pe = (const float*)d_in[0];
  const float* ge = (const float*)d_in[1];
  const float* Wq = (const float*)d_in[2];
  const float* bq = (const float*)d_in[3];
  const float* Wk = (const float*)d_in[4];
  const float* bk = (const float*)d_in[5];
  const float* Wv = (const float*)d_in[6];
  const float* bvp = (const float*)d_in[7];
  const float* W1 = (const float*)d_in[8];
  const float* b1 = (const float*)d_in[9];
  const float* w2 = (const float*)d_in[10];
  // d_in[11] = b2: uniform over n -> cancels in argmax; absent from output path.

  char* w = (char*)d_ws;
  double* Wfd = (double*)w;                              // 262144 B
  double* qbT = (double*)(w + 262144);                   // 65536 B
  float* Qm = (float*)(w + 327680);                      // 32768 B
  unsigned long long* cells =
      (unsigned long long*)(w + 360448);                 // 10240 B
  double2* c12 = (double2*)(w + 370688);                 // 2048 B
  double* kpT = (double*)(w + 372736);                   // 20,480,000 B
  double* simd = (double*)(w + 20852736);                // 10,240,000 B
  float* Vws = (float*)(w + 31092736);                   // 655,360 B
  float* scws = (float*)(w + 31748096);                  // 5,120 B (~31.8 MB total)
  float* out = (float*)d_out;

  kprep<<<dim3(321), dim3(128), 0, stream>>>(pe, Wq, bq, Wk, bk, W1, b1, w2,
                                             Wfd, qbT, Qm, cells, c12);
  kgemm<<<dim3(2500), dim3(128), 0, stream>>>(ge, Wfd, kpT);
  ksim<<<dim3(313, 16), dim3(64), 0, stream>>>(kpT, qbT, c12, simd);
  ksel2<<<dim3(1976), dim3(256), 0, stream>>>(simd, cells);
  kfinalV<<<dim3(320), dim3(256), 0, stream>>>(ge, Wv, bvp, Qm, cells, Vws, scws);
  kfinalC<<<dim3(64), dim3(128), 0, stream>>>(Vws, scws, out);
}